// Round 6
// baseline (362.489 us; speedup 1.0000x reference)
//
#include <hip/hip_runtime.h>
#include <hip/hip_bf16.h>

#define NN 4096
#define KK 64
#define AA 8
#define DD 128

// reg1 (shorts): x-halves / h1 use stride 264 (64 rows x 256 + 8 pad, 16B-aligned rows);
// a1 reuses first 8704 shorts at stride 136.
#define R1_SIZE   16896
#define XH_STRIDE 264
#define A_STRIDE  136
#define H2_STRIDE 136

typedef __bf16 bf16x8 __attribute__((ext_vector_type(8)));
typedef __bf16 bf16x2 __attribute__((ext_vector_type(2)));
typedef float  f32x4  __attribute__((ext_vector_type(4)));

__device__ __forceinline__ short f2bf(float f) {
    unsigned u = __builtin_bit_cast(unsigned, f);
    u += 0x7FFFu + ((u >> 16) & 1u);   // RNE
    return (short)(u >> 16);
}
__device__ __forceinline__ float bf2f(short s) {
    unsigned u = ((unsigned)(unsigned short)s) << 16;
    return __builtin_bit_cast(float, u);
}
// packed f32x2 -> bf16x2 (low short = a, high short = b)
__device__ __forceinline__ unsigned f2bf2(float a, float b) {
#if __has_builtin(__builtin_amdgcn_cvt_pk_bf16_f32)
    bf16x2 r = __builtin_amdgcn_cvt_pk_bf16_f32(a, b);
    return __builtin_bit_cast(unsigned, r);
#else
    return ((unsigned)(unsigned short)f2bf(a)) | (((unsigned)(unsigned short)f2bf(b)) << 16);
#endif
}
__device__ __forceinline__ void store_bf8(short* dst, float4 a, float4 b) {
    uint4 v;
    v.x = f2bf2(a.x, a.y);
    v.y = f2bf2(a.z, a.w);
    v.z = f2bf2(b.x, b.y);
    v.w = f2bf2(b.z, b.w);
    *(uint4*)dst = v;
}

// Merged prep: blocks [0,768) pack weights; blocks [768, 768+2048) compute s1 (2 nodes/block).
// Pack fragment order for mfma_f32_16x16x32_bf16 B:
// dst[((ntile*Ksteps + kstep)*64 + lane)*8 + j] = src[kstep*32+(lane>>4)*8+j][ntile*16+(lane&15)]
__global__ void prep_all(const float* __restrict__ W1, const float* __restrict__ W2,
                         const float* __restrict__ A1, const float* __restrict__ A2,
                         const int* __restrict__ nodes, const float* __restrict__ u2e,
                         const float* __restrict__ ab1,
                         short* __restrict__ W1p, short* __restrict__ W2p,
                         short* __restrict__ A1p, short* __restrict__ A2p,
                         float* __restrict__ s1g)
{
    if (blockIdx.x < 768) {
        int t = blockIdx.x * 256 + threadIdx.x;
        const float* src; short* dst; int Ncols, ksl, idx;
        if (t < 131072)      { src = W1; dst = W1p; Ncols = 256; ksl = 4; idx = t; }
        else if (t < 163840) { src = W2; dst = W2p; Ncols = 128; ksl = 3; idx = t - 131072; }
        else if (t < 180224) { src = A1; dst = A1p; Ncols = 128; ksl = 2; idx = t - 163840; }
        else                 { src = A2; dst = A2p; Ncols = 128; ksl = 2; idx = t - 180224; }
        int j     = idx & 7;
        int lane  = (idx >> 3) & 63;
        int fi    = idx >> 9;
        int kstep = fi & ((1 << ksl) - 1);
        int ntile = fi >> ksl;
        int k  = kstep * 32 + (lane >> 4) * 8 + j;
        int nn = ntile * 16 + (lane & 15);
        dst[idx] = f2bf(src[(size_t)k * Ncols + nn]);
    } else {
        // s1[n] = ab1 + u2e[nodes[n]] @ A1[128:256,:]
        __shared__ float row[2][DD];
        const int half = threadIdx.x >> 7;        // 0..1
        const int c    = threadIdx.x & 127;
        const int n    = (blockIdx.x - 768) * 2 + half;
        const int node = nodes[n];
        row[half][c] = u2e[(size_t)node * DD + c];
        __syncthreads();
        float acc = ab1[c];
#pragma unroll 8
        for (int i = 0; i < DD; ++i)
            acc = fmaf(row[half][i], A1[(size_t)(DD + i) * DD + c], acc);
        s1g[(size_t)n * DD + c] = acc;
    }
}

__launch_bounds__(512, 6)
__global__ void l2agg_mfma(
    const int* __restrict__ paths_rel,
    const int* __restrict__ paths_nbr,
    const int* __restrict__ attrs,
    const float* __restrict__ u2e,
    const float* __restrict__ r2e,
    const float* __restrict__ ua2e,
    const float* __restrict__ b1,
    const float* __restrict__ b2,
    const float* __restrict__ ab2,
    const float* __restrict__ A3,
    const float* __restrict__ ab3,
    const short* __restrict__ W1p,
    const short* __restrict__ W2p,
    const short* __restrict__ A1p,
    const short* __restrict__ A2p,
    const float* __restrict__ s1g,
    float* __restrict__ out)
{
    __shared__ short reg1[R1_SIZE];          // 33792 B: x halves / h1 (stride 264) -> a1 (stride 136)
    __shared__ short h2s[KK * H2_STRIDE];    // 17408 B, persists to final reduce
    // Time-multiplexed region (2304 B):
    //   [0..512) ints  = attrs indices (DMA, dead after b3)   | floats = per-wave logit partials (born after b7)
    //   [512..576) ints= nbr indices   (DMA, dead after b3)   | floats = softmax weights (born after b8)
    __shared__ int idx_u[576];
    float* partials = (float*)idx_u;         // 512 floats
    float* wts      = (float*)(idx_u + 512); // 64 floats

    const int n    = blockIdx.x;
    const int tid  = threadIdx.x;
    const int lane = tid & 63;
    const int wv   = tid >> 6;    // wave 0..7
    const int mr   = lane & 15;
    const int q    = lane >> 4;

    // ---------- async DMA prefetch: attrs + nbr indices -> LDS (consumed in xB staging) ----------
    {
        const int* ab = attrs + (size_t)n * KK * AA;
        __builtin_amdgcn_global_load_lds(
            (const __attribute__((address_space(1))) void*)(ab + wv * 64 + lane),
            (__attribute__((address_space(3))) void*)(idx_u + wv * 64), 4, 0, 0);
        if (wv == 0) {
            const int* nb = paths_nbr + (size_t)n * KK;
            __builtin_amdgcn_global_load_lds(
                (const __attribute__((address_space(1))) void*)(nb + lane),
                (__attribute__((address_space(3))) void*)(idx_u + 512), 4, 0, 0);
        }
    }

    // ---------- stage xA = [r1 | r2] for 64 paths (2 passes of 32 paths) ----------
#pragma unroll
    for (int pass = 0; pass < 2; ++pass) {
        const int p  = pass * 32 + (tid >> 4);
        const int t  = tid & 15;
        const int o  = t * 8;
        const int pk = n * KK + p;
        const int i0 = paths_rel[pk * 2 + 0];
        const int i1 = paths_rel[pk * 2 + 1];
        float4 r1a = *(const float4*)&r2e[(size_t)i0 * DD + o];
        float4 r1b = *(const float4*)&r2e[(size_t)i0 * DD + o + 4];
        float4 r2a = *(const float4*)&r2e[(size_t)i1 * DD + o];
        float4 r2b = *(const float4*)&r2e[(size_t)i1 * DD + o + 4];
        store_bf8(&reg1[p * XH_STRIDE + o], r1a, r1b);
        store_bf8(&reg1[p * XH_STRIDE + 128 + o], r2a, r2b);
    }
    __syncthreads();   // b1

    // ---------- GEMM1 half 1 (ks 0..7), wave -> cols wv*32..wv*32+31 (2 ntiles) ----------
    const short* W1b = W1p + wv * 2 * 16 * 512 + lane * 8;  // frag(nt,ks) = W1b[nt*8192 + ks*512]
    f32x4 acc1[4][2] = {};
    bf16x8 bfc[2], bfn[2];
#pragma unroll
    for (int nt = 0; nt < 2; ++nt) bfc[nt] = *(const bf16x8*)&W1b[nt * 8192];
#pragma unroll
    for (int ks = 0; ks < 8; ++ks) {
#pragma unroll
        for (int nt = 0; nt < 2; ++nt)
            bfn[nt] = *(const bf16x8*)&W1b[nt * 8192 + (ks + 1) * 512];
        bf16x8 af[4];
#pragma unroll
        for (int mt = 0; mt < 4; ++mt)
            af[mt] = *(const bf16x8*)&reg1[(mt * 16 + mr) * XH_STRIDE + ks * 32 + q * 8];
#pragma unroll
        for (int nt = 0; nt < 2; ++nt)
#pragma unroll
            for (int mt = 0; mt < 4; ++mt)
                acc1[mt][nt] = __builtin_amdgcn_mfma_f32_16x16x32_bf16(af[mt], bfc[nt], acc1[mt][nt], 0, 0, 0);
#pragma unroll
        for (int nt = 0; nt < 2; ++nt) bfc[nt] = bfn[nt];   // ks=7 carries ks=8 frags across staging
    }
    __syncthreads();   // b2

    // ---------- stage xB = [ne | ae]; indices from LDS ----------
#pragma unroll
    for (int pass = 0; pass < 2; ++pass) {
        const int p  = pass * 32 + (tid >> 4);
        const int t  = tid & 15;
        const int o  = t * 8;
        const int nb = idx_u[512 + p];
        float4 nea = *(const float4*)&u2e[(size_t)nb * DD + o];
        float4 neb = *(const float4*)&u2e[(size_t)nb * DD + o + 4];
        float4 aea = make_float4(0.f, 0.f, 0.f, 0.f);
        float4 aeb = make_float4(0.f, 0.f, 0.f, 0.f);
#pragma unroll
        for (int a = 0; a < AA; ++a) {
            const int ai = idx_u[p * AA + a];
            float4 va = *(const float4*)&ua2e[(size_t)ai * DD + o];
            float4 vb = *(const float4*)&ua2e[(size_t)ai * DD + o + 4];
            aea.x += va.x; aea.y += va.y; aea.z += va.z; aea.w += va.w;
            aeb.x += vb.x; aeb.y += vb.y; aeb.z += vb.z; aeb.w += vb.w;
        }
        store_bf8(&reg1[p * XH_STRIDE + o], nea, neb);
        store_bf8(&reg1[p * XH_STRIDE + 128 + o], aea, aeb);
    }
    __syncthreads();   // b3

    // ---------- GEMM1 half 2 (ks 8..15) ----------
#pragma unroll
    for (int ks = 8; ks < 16; ++ks) {
        if (ks < 15) {
#pragma unroll
            for (int nt = 0; nt < 2; ++nt)
                bfn[nt] = *(const bf16x8*)&W1b[nt * 8192 + (ks + 1) * 512];
        }
        bf16x8 af[4];
#pragma unroll
        for (int mt = 0; mt < 4; ++mt)
            af[mt] = *(const bf16x8*)&reg1[(mt * 16 + mr) * XH_STRIDE + (ks - 8) * 32 + q * 8];
#pragma unroll
        for (int nt = 0; nt < 2; ++nt)
#pragma unroll
            for (int mt = 0; mt < 4; ++mt)
                acc1[mt][nt] = __builtin_amdgcn_mfma_f32_16x16x32_bf16(af[mt], bfc[nt], acc1[mt][nt], 0, 0, 0);
        if (ks < 15) {
#pragma unroll
            for (int nt = 0; nt < 2; ++nt) bfc[nt] = bfn[nt];
        }
    }

    // preload GEMM2 ks=0 B-frag; wave -> cols wv*16..wv*16+15
    const short* W2b = W2p + wv * 8 * 512 + lane * 8;       // frag(ks) = W2b[ks*512]
    bf16x8 g2c = *(const bf16x8*)&W2b[0], g2n;
    __syncthreads();   // b4: xB consumed, reg1 free for h1

    // ---------- h1 = relu(acc1 + b1) -> reg1 (stride 264), packed cvt 2 rows at a time ----------
#pragma unroll
    for (int nt = 0; nt < 2; ++nt) {
        const int col = (wv * 2 + nt) * 16 + mr;
        const float bb = b1[col];
#pragma unroll
        for (int mt = 0; mt < 4; ++mt)
#pragma unroll
            for (int r = 0; r < 4; r += 2) {
                unsigned pk2 = f2bf2(fmaxf(acc1[mt][nt][r] + bb, 0.f),
                                     fmaxf(acc1[mt][nt][r + 1] + bb, 0.f));
                reg1[(mt * 16 + q * 4 + r)     * XH_STRIDE + col] = (short)pk2;
                reg1[(mt * 16 + q * 4 + r + 1) * XH_STRIDE + col] = (short)(pk2 >> 16);
            }
    }
    __syncthreads();   // b5

    // ---------- GEMM2: h2 = relu(h1 @ W2 + b2), 2-deep B prefetch ----------
    f32x4 acc2[4] = {};
#pragma unroll
    for (int ks = 0; ks < 8; ++ks) {
        if (ks < 7) g2n = *(const bf16x8*)&W2b[(ks + 1) * 512];
        bf16x8 af[4];
#pragma unroll
        for (int mt = 0; mt < 4; ++mt)
            af[mt] = *(const bf16x8*)&reg1[(mt * 16 + mr) * XH_STRIDE + ks * 32 + q * 8];
#pragma unroll
        for (int mt = 0; mt < 4; ++mt)
            acc2[mt] = __builtin_amdgcn_mfma_f32_16x16x32_bf16(af[mt], g2c, acc2[mt], 0, 0, 0);
        if (ks < 7) g2c = g2n;
    }

    // preload ALL GEMM3 B-frags + s1 (hidden under GEMM2 epilogue + b6)
    const short* A1b = A1p + wv * 4 * 512 + lane * 8;
    bf16x8 g3f[4];
#pragma unroll
    for (int ks = 0; ks < 4; ++ks) g3f[ks] = *(const bf16x8*)&A1b[ks * 512];
    const float s1v = s1g[(size_t)n * DD + wv * 16 + mr];

    // GEMM2 epilogue -> h2s (wave covers cols wv*16..+15)
    {
        const int col = wv * 16 + mr;
        const float bb = b2[col];
#pragma unroll
        for (int mt = 0; mt < 4; ++mt)
#pragma unroll
            for (int r = 0; r < 4; r += 2) {
                unsigned pk2 = f2bf2(fmaxf(acc2[mt][r] + bb, 0.f),
                                     fmaxf(acc2[mt][r + 1] + bb, 0.f));
                h2s[(mt * 16 + q * 4 + r)     * H2_STRIDE + col] = (short)pk2;
                h2s[(mt * 16 + q * 4 + r + 1) * H2_STRIDE + col] = (short)(pk2 >> 16);
            }
    }
    __syncthreads();   // b6

    // ---------- GEMM3: a1 = relu(h2 @ A1[:128] + s1) -> reg1 (stride 136) ----------
    {
        f32x4 acc3[4];
#pragma unroll
        for (int mt = 0; mt < 4; ++mt) {
            acc3[mt][0] = s1v; acc3[mt][1] = s1v; acc3[mt][2] = s1v; acc3[mt][3] = s1v;
        }
#pragma unroll
        for (int ks = 0; ks < 4; ++ks) {
            bf16x8 af[4];
#pragma unroll
            for (int mt = 0; mt < 4; ++mt)
                af[mt] = *(const bf16x8*)&h2s[(mt * 16 + mr) * H2_STRIDE + ks * 32 + q * 8];
#pragma unroll
            for (int mt = 0; mt < 4; ++mt)
                acc3[mt] = __builtin_amdgcn_mfma_f32_16x16x32_bf16(af[mt], g3f[ks], acc3[mt], 0, 0, 0);
        }
        // preload ALL GEMM4 B-frags (hidden under GEMM3 epilogue + b7)
        const short* A2b = A2p + wv * 4 * 512 + lane * 8;
        bf16x8 g4f[4];
#pragma unroll
        for (int ks = 0; ks < 4; ++ks) g4f[ks] = *(const bf16x8*)&A2b[ks * 512];

        {
            const int col = wv * 16 + mr;
#pragma unroll
            for (int mt = 0; mt < 4; ++mt)
#pragma unroll
                for (int r = 0; r < 4; r += 2) {
                    unsigned pk2 = f2bf2(fmaxf(acc3[mt][r], 0.f),
                                         fmaxf(acc3[mt][r + 1], 0.f));
                    reg1[(mt * 16 + q * 4 + r)     * A_STRIDE + col] = (short)pk2;
                    reg1[(mt * 16 + q * 4 + r + 1) * A_STRIDE + col] = (short)(pk2 >> 16);
                }
        }
        __syncthreads();   // b7

        // ---------- GEMM4 + in-register logits ----------
        f32x4 acc4[4];
        {
            const float bv = ab2[wv * 16 + mr];
#pragma unroll
            for (int mt = 0; mt < 4; ++mt) {
                acc4[mt][0] = bv; acc4[mt][1] = bv; acc4[mt][2] = bv; acc4[mt][3] = bv;
            }
        }
#pragma unroll
        for (int ks = 0; ks < 4; ++ks) {
            bf16x8 af[4];
#pragma unroll
            for (int mt = 0; mt < 4; ++mt)
                af[mt] = *(const bf16x8*)&reg1[(mt * 16 + mr) * A_STRIDE + ks * 32 + q * 8];
#pragma unroll
            for (int mt = 0; mt < 4; ++mt)
                acc4[mt] = __builtin_amdgcn_mfma_f32_16x16x32_bf16(af[mt], g4f[ks], acc4[mt], 0, 0, 0);
        }
        // logit partial: relu(a2) * A3[col], reduced over the 16-lane col group
        const float av = A3[wv * 16 + mr];
        float pl[4][4];
#pragma unroll
        for (int mt = 0; mt < 4; ++mt)
#pragma unroll
            for (int r = 0; r < 4; ++r)
                pl[mt][r] = fmaxf(acc4[mt][r], 0.f) * av;
#pragma unroll
        for (int off = 1; off < 16; off <<= 1)
#pragma unroll
            for (int mt = 0; mt < 4; ++mt)
#pragma unroll
                for (int r = 0; r < 4; ++r)
                    pl[mt][r] += __shfl_xor(pl[mt][r], off, 64);
        if (mr == 0) {
#pragma unroll
            for (int mt = 0; mt < 4; ++mt)
#pragma unroll
                for (int r = 0; r < 4; ++r)
                    partials[wv * KK + mt * 16 + q * 4 + r] = pl[mt][r];
        }
    }
    __syncthreads();   // b8

    // ---------- logits sum + softmax (wave 0) ----------
    if (tid < KK) {
        float l = ab3[0];
#pragma unroll
        for (int w = 0; w < 8; ++w) l += partials[w * KK + tid];
        float m = l;
#pragma unroll
        for (int off = 32; off > 0; off >>= 1) m = fmaxf(m, __shfl_xor(m, off, 64));
        float e = expf(l - m);
        float s = e;
#pragma unroll
        for (int off = 32; off > 0; off >>= 1) s += __shfl_xor(s, off, 64);
        wts[tid] = e / s;
    }
    __syncthreads();   // b9

    // ---------- out[n] = sum_k w[k] * h2[k] ----------
    if (tid < DD) {
        float acc = 0.f;
#pragma unroll 8
        for (int k = 0; k < KK; ++k)
            acc = fmaf(wts[k], bf2f(h2s[k * H2_STRIDE + tid]), acc);
        out[(size_t)n * DD + tid] = acc;
    }
}

extern "C" void kernel_launch(void* const* d_in, const int* in_sizes, int n_in,
                              void* d_out, int out_size, void* d_ws, size_t ws_size,
                              hipStream_t stream)
{
    const int*   nodes     = (const int*)d_in[0];
    const int*   paths_rel = (const int*)d_in[1];
    const int*   paths_nbr = (const int*)d_in[2];
    const int*   attrs     = (const int*)d_in[3];
    const float* u2e  = (const float*)d_in[4];
    const float* r2e  = (const float*)d_in[5];
    const float* ua2e = (const float*)d_in[6];
    const float* W1   = (const float*)d_in[7];
    const float* b1   = (const float*)d_in[8];
    const float* W2   = (const float*)d_in[9];
    const float* b2   = (const float*)d_in[10];
    const float* A1   = (const float*)d_in[11];
    const float* ab1  = (const float*)d_in[12];
    const float* A2   = (const float*)d_in[13];
    const float* ab2  = (const float*)d_in[14];
    const float* A3   = (const float*)d_in[15];
    const float* ab3  = (const float*)d_in[16];
    float* out = (float*)d_out;

    // ws layout: shorts W1p 131072 | W2p 32768 | A1p 16384 | A2p 16384 (=384 KB),
    // then s1g float[4096*128] (2 MB)
    short* wsp = (short*)d_ws;
    short* W1p = wsp;
    short* W2p = wsp + 131072;
    short* A1p = wsp + 163840;
    short* A2p = wsp + 180224;
    float* s1g = (float*)((char*)d_ws + 393216);

    hipLaunchKernelGGL(prep_all, dim3(768 + 2048), dim3(256), 0, stream,
                       W1, W2, A1, A2, nodes, u2e, ab1,
                       W1p, W2p, A1p, A2p, s1g);
    hipLaunchKernelGGL(l2agg_mfma, dim3(NN), dim3(512), 0, stream,
                       paths_rel, paths_nbr, attrs, u2e, r2e, ua2e,
                       b1, b2, ab2, A3, ab3,
                       W1p, W2p, A1p, A2p, s1g, out);
}

// Round 7
// 295.089 us; speedup vs baseline: 1.2284x; 1.2284x over previous
//
#include <hip/hip_runtime.h>
#include <hip/hip_bf16.h>

#define NN 4096
#define KK 64
#define AA 8
#define DD 128

// reg1 (shorts): x-halves / h1 use stride 264 (64 rows x 256 + 8 pad, 16B-aligned rows);
// a1 reuses first 8704 shorts at stride 136.
#define R1_SIZE   16896
#define XH_STRIDE 264
#define A_STRIDE  136
#define H2_STRIDE 136

typedef __bf16 bf16x8 __attribute__((ext_vector_type(8)));
typedef __bf16 bf16x2 __attribute__((ext_vector_type(2)));
typedef float  f32x4  __attribute__((ext_vector_type(4)));

__device__ __forceinline__ short f2bf(float f) {
    unsigned u = __builtin_bit_cast(unsigned, f);
    u += 0x7FFFu + ((u >> 16) & 1u);   // RNE
    return (short)(u >> 16);
}
__device__ __forceinline__ float bf2f(short s) {
    unsigned u = ((unsigned)(unsigned short)s) << 16;
    return __builtin_bit_cast(float, u);
}
// packed f32x2 -> bf16x2 (low short = a, high short = b)
__device__ __forceinline__ unsigned f2bf2(float a, float b) {
#if __has_builtin(__builtin_amdgcn_cvt_pk_bf16_f32)
    bf16x2 r = __builtin_amdgcn_cvt_pk_bf16_f32(a, b);
    return __builtin_bit_cast(unsigned, r);
#else
    return ((unsigned)(unsigned short)f2bf(a)) | (((unsigned)(unsigned short)f2bf(b)) << 16);
#endif
}
__device__ __forceinline__ void store_bf8(short* dst, float4 a, float4 b) {
    uint4 v;
    v.x = f2bf2(a.x, a.y);
    v.y = f2bf2(a.z, a.w);
    v.z = f2bf2(b.x, b.y);
    v.w = f2bf2(b.z, b.w);
    *(uint4*)dst = v;
}

// Merged prep: blocks [0,768) pack weights; blocks [768, 768+2048) compute s1 (2 nodes/block).
// Pack fragment order for mfma_f32_16x16x32_bf16 B:
// dst[((ntile*Ksteps + kstep)*64 + lane)*8 + j] = src[kstep*32+(lane>>4)*8+j][ntile*16+(lane&15)]
__global__ void prep_all(const float* __restrict__ W1, const float* __restrict__ W2,
                         const float* __restrict__ A1, const float* __restrict__ A2,
                         const int* __restrict__ nodes, const float* __restrict__ u2e,
                         const float* __restrict__ ab1,
                         short* __restrict__ W1p, short* __restrict__ W2p,
                         short* __restrict__ A1p, short* __restrict__ A2p,
                         float* __restrict__ s1g)
{
    if (blockIdx.x < 768) {
        int t = blockIdx.x * 256 + threadIdx.x;
        const float* src; short* dst; int Ncols, ksl, idx;
        if (t < 131072)      { src = W1; dst = W1p; Ncols = 256; ksl = 4; idx = t; }
        else if (t < 163840) { src = W2; dst = W2p; Ncols = 128; ksl = 3; idx = t - 131072; }
        else if (t < 180224) { src = A1; dst = A1p; Ncols = 128; ksl = 2; idx = t - 163840; }
        else                 { src = A2; dst = A2p; Ncols = 128; ksl = 2; idx = t - 180224; }
        int j     = idx & 7;
        int lane  = (idx >> 3) & 63;
        int fi    = idx >> 9;
        int kstep = fi & ((1 << ksl) - 1);
        int ntile = fi >> ksl;
        int k  = kstep * 32 + (lane >> 4) * 8 + j;
        int nn = ntile * 16 + (lane & 15);
        dst[idx] = f2bf(src[(size_t)k * Ncols + nn]);
    } else {
        // s1[n] = ab1 + u2e[nodes[n]] @ A1[128:256,:]
        __shared__ float row[2][DD];
        const int half = threadIdx.x >> 7;        // 0..1
        const int c    = threadIdx.x & 127;
        const int n    = (blockIdx.x - 768) * 2 + half;
        const int node = nodes[n];
        row[half][c] = u2e[(size_t)node * DD + c];
        __syncthreads();
        float acc = ab1[c];
#pragma unroll 8
        for (int i = 0; i < DD; ++i)
            acc = fmaf(row[half][i], A1[(size_t)(DD + i) * DD + c], acc);
        s1g[(size_t)n * DD + c] = acc;
    }
}

// NOTE: launch_bounds MUST stay (512,4). (512,6) capped regs at ~85/wave -> 40 arch
// VGPRs -> accumulator spill to scratch: +280 MB FETCH / +287 MB WRITE, 203->264 us (R6).
// At (512,4) codegen lands ~64 VGPR; with LDS at 53.5 KB the HW can still schedule
// 3 blocks/CU when the register file permits — without forcing the allocator.
__launch_bounds__(512, 4)
__global__ void l2agg_mfma(
    const int* __restrict__ paths_rel,
    const int* __restrict__ paths_nbr,
    const int* __restrict__ attrs,
    const float* __restrict__ u2e,
    const float* __restrict__ r2e,
    const float* __restrict__ ua2e,
    const float* __restrict__ b1,
    const float* __restrict__ b2,
    const float* __restrict__ ab2,
    const float* __restrict__ A3,
    const float* __restrict__ ab3,
    const short* __restrict__ W1p,
    const short* __restrict__ W2p,
    const short* __restrict__ A1p,
    const short* __restrict__ A2p,
    const float* __restrict__ s1g,
    float* __restrict__ out)
{
    __shared__ short reg1[R1_SIZE];          // 33792 B: x halves / h1 (stride 264) -> a1 (stride 136)
    __shared__ short h2s[KK * H2_STRIDE];    // 17408 B, persists to final reduce
    // Time-multiplexed region (2304 B):
    //   [0..512) ints  = attrs indices (DMA, dead after b3)   | floats = per-wave logit partials (born after b7)
    //   [512..576) ints= nbr indices   (DMA, dead after b3)   | floats = softmax weights (born after b8)
    __shared__ int idx_u[576];
    float* partials = (float*)idx_u;         // 512 floats
    float* wts      = (float*)(idx_u + 512); // 64 floats

    const int n    = blockIdx.x;
    const int tid  = threadIdx.x;
    const int lane = tid & 63;
    const int wv   = tid >> 6;    // wave 0..7
    const int mr   = lane & 15;
    const int q    = lane >> 4;

    // ---------- async DMA prefetch: attrs + nbr indices -> LDS (consumed in xB staging) ----------
    {
        const int* ab = attrs + (size_t)n * KK * AA;
        __builtin_amdgcn_global_load_lds(
            (const __attribute__((address_space(1))) void*)(ab + wv * 64 + lane),
            (__attribute__((address_space(3))) void*)(idx_u + wv * 64), 4, 0, 0);
        if (wv == 0) {
            const int* nb = paths_nbr + (size_t)n * KK;
            __builtin_amdgcn_global_load_lds(
                (const __attribute__((address_space(1))) void*)(nb + lane),
                (__attribute__((address_space(3))) void*)(idx_u + 512), 4, 0, 0);
        }
    }

    // ---------- stage xA = [r1 | r2] for 64 paths (2 passes of 32 paths) ----------
#pragma unroll
    for (int pass = 0; pass < 2; ++pass) {
        const int p  = pass * 32 + (tid >> 4);
        const int t  = tid & 15;
        const int o  = t * 8;
        const int pk = n * KK + p;
        const int i0 = paths_rel[pk * 2 + 0];
        const int i1 = paths_rel[pk * 2 + 1];
        float4 r1a = *(const float4*)&r2e[(size_t)i0 * DD + o];
        float4 r1b = *(const float4*)&r2e[(size_t)i0 * DD + o + 4];
        float4 r2a = *(const float4*)&r2e[(size_t)i1 * DD + o];
        float4 r2b = *(const float4*)&r2e[(size_t)i1 * DD + o + 4];
        store_bf8(&reg1[p * XH_STRIDE + o], r1a, r1b);
        store_bf8(&reg1[p * XH_STRIDE + 128 + o], r2a, r2b);
    }
    __syncthreads();   // b1

    // ---------- GEMM1 half 1 (ks 0..7), wave -> cols wv*32..wv*32+31 (2 ntiles) ----------
    const short* W1b = W1p + wv * 2 * 16 * 512 + lane * 8;  // frag(nt,ks) = W1b[nt*8192 + ks*512]
    f32x4 acc1[4][2] = {};
    bf16x8 bfc[2], bfn[2];
#pragma unroll
    for (int nt = 0; nt < 2; ++nt) bfc[nt] = *(const bf16x8*)&W1b[nt * 8192];
#pragma unroll
    for (int ks = 0; ks < 8; ++ks) {
#pragma unroll
        for (int nt = 0; nt < 2; ++nt)
            bfn[nt] = *(const bf16x8*)&W1b[nt * 8192 + (ks + 1) * 512];
        bf16x8 af[4];
#pragma unroll
        for (int mt = 0; mt < 4; ++mt)
            af[mt] = *(const bf16x8*)&reg1[(mt * 16 + mr) * XH_STRIDE + ks * 32 + q * 8];
#pragma unroll
        for (int nt = 0; nt < 2; ++nt)
#pragma unroll
            for (int mt = 0; mt < 4; ++mt)
                acc1[mt][nt] = __builtin_amdgcn_mfma_f32_16x16x32_bf16(af[mt], bfc[nt], acc1[mt][nt], 0, 0, 0);
#pragma unroll
        for (int nt = 0; nt < 2; ++nt) bfc[nt] = bfn[nt];   // ks=7 carries ks=8 frags across staging
    }
    __syncthreads();   // b2

    // ---------- stage xB = [ne | ae]; indices from LDS ----------
#pragma unroll
    for (int pass = 0; pass < 2; ++pass) {
        const int p  = pass * 32 + (tid >> 4);
        const int t  = tid & 15;
        const int o  = t * 8;
        const int nb = idx_u[512 + p];
        float4 nea = *(const float4*)&u2e[(size_t)nb * DD + o];
        float4 neb = *(const float4*)&u2e[(size_t)nb * DD + o + 4];
        float4 aea = make_float4(0.f, 0.f, 0.f, 0.f);
        float4 aeb = make_float4(0.f, 0.f, 0.f, 0.f);
#pragma unroll
        for (int a = 0; a < AA; ++a) {
            const int ai = idx_u[p * AA + a];
            float4 va = *(const float4*)&ua2e[(size_t)ai * DD + o];
            float4 vb = *(const float4*)&ua2e[(size_t)ai * DD + o + 4];
            aea.x += va.x; aea.y += va.y; aea.z += va.z; aea.w += va.w;
            aeb.x += vb.x; aeb.y += vb.y; aeb.z += vb.z; aeb.w += vb.w;
        }
        store_bf8(&reg1[p * XH_STRIDE + o], nea, neb);
        store_bf8(&reg1[p * XH_STRIDE + 128 + o], aea, aeb);
    }
    __syncthreads();   // b3

    // ---------- GEMM1 half 2 (ks 8..15) ----------
#pragma unroll
    for (int ks = 8; ks < 16; ++ks) {
        if (ks < 15) {
#pragma unroll
            for (int nt = 0; nt < 2; ++nt)
                bfn[nt] = *(const bf16x8*)&W1b[nt * 8192 + (ks + 1) * 512];
        }
        bf16x8 af[4];
#pragma unroll
        for (int mt = 0; mt < 4; ++mt)
            af[mt] = *(const bf16x8*)&reg1[(mt * 16 + mr) * XH_STRIDE + (ks - 8) * 32 + q * 8];
#pragma unroll
        for (int nt = 0; nt < 2; ++nt)
#pragma unroll
            for (int mt = 0; mt < 4; ++mt)
                acc1[mt][nt] = __builtin_amdgcn_mfma_f32_16x16x32_bf16(af[mt], bfc[nt], acc1[mt][nt], 0, 0, 0);
        if (ks < 15) {
#pragma unroll
            for (int nt = 0; nt < 2; ++nt) bfc[nt] = bfn[nt];
        }
    }

    // preload GEMM2 ks=0 B-frag; wave -> cols wv*16..wv*16+15
    const short* W2b = W2p + wv * 8 * 512 + lane * 8;       // frag(ks) = W2b[ks*512]
    bf16x8 g2c = *(const bf16x8*)&W2b[0], g2n;
    __syncthreads();   // b4: xB consumed, reg1 free for h1

    // ---------- h1 = relu(acc1 + b1) -> reg1 (stride 264), packed cvt ----------
#pragma unroll
    for (int nt = 0; nt < 2; ++nt) {
        const int col = (wv * 2 + nt) * 16 + mr;
        const float bb = b1[col];
#pragma unroll
        for (int mt = 0; mt < 4; ++mt)
#pragma unroll
            for (int r = 0; r < 4; r += 2) {
                unsigned pk2 = f2bf2(fmaxf(acc1[mt][nt][r] + bb, 0.f),
                                     fmaxf(acc1[mt][nt][r + 1] + bb, 0.f));
                reg1[(mt * 16 + q * 4 + r)     * XH_STRIDE + col] = (short)pk2;
                reg1[(mt * 16 + q * 4 + r + 1) * XH_STRIDE + col] = (short)(pk2 >> 16);
            }
    }
    __syncthreads();   // b5

    // ---------- GEMM2: h2 = relu(h1 @ W2 + b2), 2-deep B prefetch ----------
    f32x4 acc2[4] = {};
#pragma unroll
    for (int ks = 0; ks < 8; ++ks) {
        if (ks < 7) g2n = *(const bf16x8*)&W2b[(ks + 1) * 512];
        bf16x8 af[4];
#pragma unroll
        for (int mt = 0; mt < 4; ++mt)
            af[mt] = *(const bf16x8*)&reg1[(mt * 16 + mr) * XH_STRIDE + ks * 32 + q * 8];
#pragma unroll
        for (int mt = 0; mt < 4; ++mt)
            acc2[mt] = __builtin_amdgcn_mfma_f32_16x16x32_bf16(af[mt], g2c, acc2[mt], 0, 0, 0);
        if (ks < 7) g2c = g2n;
    }

    // preload ALL GEMM3 B-frags + s1 (hidden under GEMM2 epilogue + b6)
    const short* A1b = A1p + wv * 4 * 512 + lane * 8;
    bf16x8 g3f[4];
#pragma unroll
    for (int ks = 0; ks < 4; ++ks) g3f[ks] = *(const bf16x8*)&A1b[ks * 512];
    const float s1v = s1g[(size_t)n * DD + wv * 16 + mr];

    // GEMM2 epilogue -> h2s (wave covers cols wv*16..+15)
    {
        const int col = wv * 16 + mr;
        const float bb = b2[col];
#pragma unroll
        for (int mt = 0; mt < 4; ++mt)
#pragma unroll
            for (int r = 0; r < 4; r += 2) {
                unsigned pk2 = f2bf2(fmaxf(acc2[mt][r] + bb, 0.f),
                                     fmaxf(acc2[mt][r + 1] + bb, 0.f));
                h2s[(mt * 16 + q * 4 + r)     * H2_STRIDE + col] = (short)pk2;
                h2s[(mt * 16 + q * 4 + r + 1) * H2_STRIDE + col] = (short)(pk2 >> 16);
            }
    }
    __syncthreads();   // b6

    // ---------- GEMM3: a1 = relu(h2 @ A1[:128] + s1) -> reg1 (stride 136) ----------
    {
        f32x4 acc3[4];
#pragma unroll
        for (int mt = 0; mt < 4; ++mt) {
            acc3[mt][0] = s1v; acc3[mt][1] = s1v; acc3[mt][2] = s1v; acc3[mt][3] = s1v;
        }
#pragma unroll
        for (int ks = 0; ks < 4; ++ks) {
            bf16x8 af[4];
#pragma unroll
            for (int mt = 0; mt < 4; ++mt)
                af[mt] = *(const bf16x8*)&h2s[(mt * 16 + mr) * H2_STRIDE + ks * 32 + q * 8];
#pragma unroll
            for (int mt = 0; mt < 4; ++mt)
                acc3[mt] = __builtin_amdgcn_mfma_f32_16x16x32_bf16(af[mt], g3f[ks], acc3[mt], 0, 0, 0);
        }
        // preload ALL GEMM4 B-frags (hidden under GEMM3 epilogue + b7)
        const short* A2b = A2p + wv * 4 * 512 + lane * 8;
        bf16x8 g4f[4];
#pragma unroll
        for (int ks = 0; ks < 4; ++ks) g4f[ks] = *(const bf16x8*)&A2b[ks * 512];

        {
            const int col = wv * 16 + mr;
#pragma unroll
            for (int mt = 0; mt < 4; ++mt)
#pragma unroll
                for (int r = 0; r < 4; r += 2) {
                    unsigned pk2 = f2bf2(fmaxf(acc3[mt][r], 0.f),
                                         fmaxf(acc3[mt][r + 1], 0.f));
                    reg1[(mt * 16 + q * 4 + r)     * A_STRIDE + col] = (short)pk2;
                    reg1[(mt * 16 + q * 4 + r + 1) * A_STRIDE + col] = (short)(pk2 >> 16);
                }
        }
        __syncthreads();   // b7

        // ---------- GEMM4 + in-register logits ----------
        f32x4 acc4[4];
        {
            const float bv = ab2[wv * 16 + mr];
#pragma unroll
            for (int mt = 0; mt < 4; ++mt) {
                acc4[mt][0] = bv; acc4[mt][1] = bv; acc4[mt][2] = bv; acc4[mt][3] = bv;
            }
        }
#pragma unroll
        for (int ks = 0; ks < 4; ++ks) {
            bf16x8 af[4];
#pragma unroll
            for (int mt = 0; mt < 4; ++mt)
                af[mt] = *(const bf16x8*)&reg1[(mt * 16 + mr) * A_STRIDE + ks * 32 + q * 8];
#pragma unroll
            for (int mt = 0; mt < 4; ++mt)
                acc4[mt] = __builtin_amdgcn_mfma_f32_16x16x32_bf16(af[mt], g4f[ks], acc4[mt], 0, 0, 0);
        }
        // logit partial: relu(a2) * A3[col], reduced over the 16-lane col group
        const float av = A3[wv * 16 + mr];
        float pl[4][4];
#pragma unroll
        for (int mt = 0; mt < 4; ++mt)
#pragma unroll
            for (int r = 0; r < 4; ++r)
                pl[mt][r] = fmaxf(acc4[mt][r], 0.f) * av;
#pragma unroll
        for (int off = 1; off < 16; off <<= 1)
#pragma unroll
            for (int mt = 0; mt < 4; ++mt)
#pragma unroll
                for (int r = 0; r < 4; ++r)
                    pl[mt][r] += __shfl_xor(pl[mt][r], off, 64);
        if (mr == 0) {
#pragma unroll
            for (int mt = 0; mt < 4; ++mt)
#pragma unroll
                for (int r = 0; r < 4; ++r)
                    partials[wv * KK + mt * 16 + q * 4 + r] = pl[mt][r];
        }
    }
    __syncthreads();   // b8

    // ---------- logits sum + softmax (wave 0) ----------
    if (tid < KK) {
        float l = ab3[0];
#pragma unroll
        for (int w = 0; w < 8; ++w) l += partials[w * KK + tid];
        float m = l;
#pragma unroll
        for (int off = 32; off > 0; off >>= 1) m = fmaxf(m, __shfl_xor(m, off, 64));
        float e = expf(l - m);
        float s = e;
#pragma unroll
        for (int off = 32; off > 0; off >>= 1) s += __shfl_xor(s, off, 64);
        wts[tid] = e / s;
    }
    __syncthreads();   // b9

    // ---------- out[n] = sum_k w[k] * h2[k] ----------
    if (tid < DD) {
        float acc = 0.f;
#pragma unroll 8
        for (int k = 0; k < KK; ++k)
            acc = fmaf(wts[k], bf2f(h2s[k * H2_STRIDE + tid]), acc);
        out[(size_t)n * DD + tid] = acc;
    }
}

extern "C" void kernel_launch(void* const* d_in, const int* in_sizes, int n_in,
                              void* d_out, int out_size, void* d_ws, size_t ws_size,
                              hipStream_t stream)
{
    const int*   nodes     = (const int*)d_in[0];
    const int*   paths_rel = (const int*)d_in[1];
    const int*   paths_nbr = (const int*)d_in[2];
    const int*   attrs     = (const int*)d_in[3];
    const float* u2e  = (const float*)d_in[4];
    const float* r2e  = (const float*)d_in[5];
    const float* ua2e = (const float*)d_in[6];
    const float* W1   = (const float*)d_in[7];
    const float* b1   = (const float*)d_in[8];
    const float* W2   = (const float*)d_in[9];
    const float* b2   = (const float*)d_in[10];
    const float* A1   = (const float*)d_in[11];
    const float* ab1  = (const float*)d_in[12];
    const float* A2   = (const float*)d_in[13];
    const float* ab2  = (const float*)d_in[14];
    const float* A3   = (const float*)d_in[15];
    const float* ab3  = (const float*)d_in[16];
    float* out = (float*)d_out;

    // ws layout: shorts W1p 131072 | W2p 32768 | A1p 16384 | A2p 16384 (=384 KB),
    // then s1g float[4096*128] (2 MB)
    short* wsp = (short*)d_ws;
    short* W1p = wsp;
    short* W2p = wsp + 131072;
    short* A1p = wsp + 163840;
    short* A2p = wsp + 180224;
    float* s1g = (float*)((char*)d_ws + 393216);

    hipLaunchKernelGGL(prep_all, dim3(768 + 2048), dim3(256), 0, stream,
                       W1, W2, A1, A2, nodes, u2e, ab1,
                       W1p, W2p, A1p, A2p, s1g);
    hipLaunchKernelGGL(l2agg_mfma, dim3(NN), dim3(512), 0, stream,
                       paths_rel, paths_nbr, attrs, u2e, r2e, ua2e,
                       b1, b2, ab2, A3, ab3,
                       W1p, W2p, A1p, A2p, s1g, out);
}